// Round 11
// baseline (3345.580 us; speedup 1.0000x reference)
//
#include <hip/hip_runtime.h>

typedef __attribute__((ext_vector_type(8))) short short8;
typedef __attribute__((ext_vector_type(4))) float f32x4;

#define DEV static __device__ __forceinline__

DEV unsigned short f2b(float f) {
    union { float f; unsigned u; } v; v.f = f;
    unsigned r = (v.u + 0x7FFFu + ((v.u >> 16) & 1u)) >> 16;
    return (unsigned short)r;
}
DEV float b2f(unsigned short s) {
    union { unsigned u; float f; } v; v.u = ((unsigned)s) << 16;
    return v.f;
}
DEV float sigm(float x) { return 1.0f / (1.0f + __expf(-x)); }

// ---------------- converts ----------------

__global__ void k_f2b(const float* __restrict__ src, unsigned short* __restrict__ dst, int n4) {
    int i = blockIdx.x * blockDim.x + threadIdx.x;
    if (i < n4) {
        float4 v = ((const float4*)src)[i];
        ushort4 o;
        o.x = f2b(v.x); o.y = f2b(v.y); o.z = f2b(v.z); o.w = f2b(v.w);
        ((ushort4*)dst)[i] = o;
    }
}

// dst[(4j+g)][k] = bf16(src[(g*1024+j)][k]); Kq = K/4
__global__ void k_perm(const float* __restrict__ src, unsigned short* __restrict__ dst, int Kq) {
    int i = blockIdx.x * blockDim.x + threadIdx.x;
    int total = 4096 * Kq;
    if (i >= total) return;
    int rp = i / Kq, kq = i - rp * Kq;
    int j = rp >> 2, g = rp & 3;
    float4 v = ((const float4*)src)[(size_t)(g * 1024 + j) * Kq + kq];
    ushort4 o;
    o.x = f2b(v.x); o.y = f2b(v.y); o.z = f2b(v.z); o.w = f2b(v.w);
    ((ushort4*)dst)[(size_t)rp * Kq + kq] = o;
}

__global__ void k_bias(const float* __restrict__ bi0, const float* __restrict__ bh0,
                       const float* __restrict__ bi1, const float* __restrict__ bh1,
                       float* __restrict__ d0, float* __restrict__ d1) {
    int i = blockIdx.x * blockDim.x + threadIdx.x;
    if (i < 4096) {
        int j = i >> 2, g = i & 3, s = g * 1024 + j;
        d0[i] = bi0[s] + bh0[s];
        d1[i] = bi1[s] + bh1[s];
    }
}

// writes initial h (packed 2xbf16) into parity-1 buffers; c as fp32
__global__ void k_init(const float* __restrict__ hx, const float* __restrict__ cx,
                       unsigned* __restrict__ hB0, unsigned* __restrict__ hB1,
                       float* __restrict__ c0, float* __restrict__ c1) {
    int i = blockIdx.x * blockDim.x + threadIdx.x;
    if (i < 128 * 512) {
        int b = i >> 9, j = i & 511;
        const float* p0 = hx + (size_t)b * 1024 + j * 2;
        const float* p1 = hx + 131072 + (size_t)b * 1024 + j * 2;
        hB0[i] = (unsigned)f2b(p0[0]) | ((unsigned)f2b(p0[1]) << 16);
        hB1[i] = (unsigned)f2b(p1[0]) | ((unsigned)f2b(p1[1]) << 16);
        c0[i * 2] = cx[i * 2];
        c0[i * 2 + 1] = cx[i * 2 + 1];
        c1[i * 2] = cx[131072 + i * 2];
        c1[i * 2 + 1] = cx[131072 + i * 2 + 1];
    }
}

// ---------------- xg GEMM: out[v][n] = sum_k A[row(v)][k] * W[n][k] ----------------
__global__ __launch_bounds__(256) void k_gemm(
    const unsigned short* __restrict__ A, const unsigned short* __restrict__ W,
    unsigned short* __restrict__ out, int K, int t0, int TC) {
    __shared__ unsigned short ldsA[128 * 40];
    __shared__ unsigned short ldsB[128 * 40];
    const int tid = threadIdx.x;
    const int w = tid >> 6, l = tid & 63;
    const int wm = w >> 1, wn = w & 1;
    const int bm = blockIdx.x, bn = blockIdx.y;
    const int lr = l & 15, lk = (l >> 4) * 8;

    const int row0 = tid >> 2, inb = (tid & 3) << 4;
    const int row1 = row0 + 64;
    const int v0 = bm * 128 + row0, v1 = bm * 128 + row1;
    const size_t ar0 = (size_t)((v0 / TC) * 256 + t0 + (v0 % TC));
    const size_t ar1 = (size_t)((v1 / TC) * 256 + t0 + (v1 % TC));
    const size_t br0 = (size_t)(bn * 128 + row0);
    const size_t br1 = (size_t)(bn * 128 + row1);

    f32x4 acc[4][4];
#pragma unroll
    for (int a = 0; a < 4; a++)
#pragma unroll
        for (int b = 0; b < 4; b++) acc[a][b] = (f32x4){0.f, 0.f, 0.f, 0.f};

    for (int ks = 0; ks < K; ks += 32) {
        uint4 a0 = *(const uint4*)((const char*)A + (ar0 * K + ks) * 2 + inb);
        uint4 a1 = *(const uint4*)((const char*)A + (ar1 * K + ks) * 2 + inb);
        uint4 b0 = *(const uint4*)((const char*)W + (br0 * K + ks) * 2 + inb);
        uint4 b1 = *(const uint4*)((const char*)W + (br1 * K + ks) * 2 + inb);
        *(uint4*)((char*)ldsA + row0 * 80 + inb) = a0;
        *(uint4*)((char*)ldsA + row1 * 80 + inb) = a1;
        *(uint4*)((char*)ldsB + row0 * 80 + inb) = b0;
        *(uint4*)((char*)ldsB + row1 * 80 + inb) = b1;
        __syncthreads();
        short8 af[4], bf[4];
#pragma unroll
        for (int mt = 0; mt < 4; mt++)
            af[mt] = *(const short8*)((const char*)ldsA + (wm * 64 + mt * 16 + lr) * 80 + lk * 2);
#pragma unroll
        for (int nt = 0; nt < 4; nt++)
            bf[nt] = *(const short8*)((const char*)ldsB + (wn * 64 + nt * 16 + lr) * 80 + lk * 2);
#pragma unroll
        for (int mt = 0; mt < 4; mt++)
#pragma unroll
            for (int nt = 0; nt < 4; nt++)
                acc[mt][nt] = __builtin_amdgcn_mfma_f32_16x16x32_bf16(af[mt], bf[nt], acc[mt][nt], 0, 0, 0);
        __syncthreads();
    }

#pragma unroll
    for (int mt = 0; mt < 4; mt++)
#pragma unroll
        for (int nt = 0; nt < 4; nt++)
#pragma unroll
            for (int v4 = 0; v4 < 4; v4++) {
                int vr = bm * 128 + wm * 64 + mt * 16 + (l >> 4) * 4 + v4;
                int col = bn * 128 + wn * 64 + nt * 16 + lr;
                out[(size_t)vr * 4096 + col] = f2b(acc[mt][nt][v4]);
            }
}

// ---------------- persistent recurrent kernel (no-reduce col-split) ----------------
// 256 wgs (1/CU), 512 threads (8 waves). 8 groups x 32 wgs.
// wg = (g: 16 batch rows) x (nb: 128 gate cols). Waves = COL-split: wave wv owns 16
// gate cols (nb*128 + wv*16..+16), full K=1024, acc = single f32x4 -> NO cross-wave
// reduce, no P buffers. h tile (16 rows x 1024, 32 KB) staged into LDS cooperatively
// each tick (coalesced coherent u64 loads). W: rows 0..47 in LDS (pitch 2064B, waves
// 0-2), rows 48..127 in regs (waves 3-7, wreg[32] = 128 VGPR, static-indexed).
// Epilogue: 4x4 shfl transpose within 4-lane groups puts all 4 gates of one cell in
// one lane -> 512 threads x 1 cell each. 2 barriers/tick (A-tile ready; store drain).
// Flag protocol from r10 (proven): per-wg flags 64B apart, absolute tag t+1,
// lane-parallel poll (lane l polls flag[l&31]) + __all. Atomic loads stay in
// per-iteration immediately-consumed shape (r6-r8 batching quarantine).
template<int LAYER>
__global__ __launch_bounds__(512, 2) void k_lstm(
    const unsigned short* __restrict__ Wh,     // [4096][1024] bf16 gate-interleaved
    const unsigned short* __restrict__ xg,     // chunk: + b*(TC*4096) + dt*4096
    const float* __restrict__ bias,            // [4096]
    float* __restrict__ cbuf,                  // [128*1024] fp32
    unsigned* __restrict__ hA,                 // parity-0 h (packed 2xbf16) [128][512]
    unsigned* __restrict__ hB,                 // parity-1 h
    unsigned short* __restrict__ y0,           // layer0: h history [B][T][H] bf16 (null for L1)
    float* __restrict__ out,                   // layer1 only
    unsigned* __restrict__ flags,              // 8 groups x 32 wgs, stride 16 u32 (64B)
    int t0, int TC)
{
    extern __shared__ char smem[];
    char* ldsW = smem;                 // 48 rows x 2064 B
    char* ldsA = smem + 48 * 2064;     // 16 rows x 2064 B

    const int tid = threadIdx.x;
    const int g  = (int)blockIdx.x >> 5;   // 0..7: batch rows g*16..+16
    const int nb = (int)blockIdx.x & 31;   // 0..31: gate cols nb*128..+128
    const int wv = tid >> 6;               // wave 0..7 = 16-col block
    const int l  = tid & 63;
    const int lr = l & 15, lq = l >> 4;

    // stage LDS W: gate-rows nb*128..+48, 48 rows x 2048B at pitch 2064B
    {
        const char* src = (const char*)(Wh + (size_t)nb * 128 * 1024);
#pragma unroll
        for (int it = 0; it < 12; it++) {
            int idx = it * 512 + tid;          // 6144 16B-chunks = 48 x 128
            int row = idx >> 7, inr = (idx & 127) << 4;
            *(uint4*)(ldsW + row * 2064 + inr) = *(const uint4*)(src + (size_t)row * 2048 + inr);
        }
    }
    // reg W for waves 3..7: rows 48 + (wv-3)*16, full K. 32 x short8 = 128 VGPR.
    short8 wreg[32];
    if (wv >= 3) {
        const unsigned short* src = Wh + ((size_t)nb * 128 + 48 + (wv - 3) * 16 + lr) * 1024;
#pragma unroll
        for (int kk = 0; kk < 32; kk++)
            wreg[kk] = *(const short8*)(src + kk * 32 + lq * 8);
    }

    // per-lane cell mapping (after transpose): row16 = (l>>4)*4 + (l&3), unit via (l>>2)&3
    const int row16 = (l >> 4) * 4 + (l & 3);
    const int b = g * 16 + row16;
    const int u_local = (l >> 2) & 3;
    const int unit = nb * 32 + wv * 4 + u_local;
    const int ec = unit * 4;
    float c2 = cbuf[(size_t)b * 1024 + unit];
    const float4 bs = *(const float4*)(bias + ec);

    const size_t agbase = (size_t)g * 16 * 256;  // h tile base, u64 units

    const unsigned* fp = flags + (size_t)(g * 32 + (l & 31)) * 16;
    unsigned* fmine = flags + (size_t)(g * 32 + nb) * 16;

    __syncthreads();

    for (int dt = 0; dt < TC; dt++) {
        const int t = t0 + dt;
        // prefetch xg for this lane's cell (independent of h) — overlaps the poll
        uint2 xv = *(const uint2*)(xg + (size_t)b * ((size_t)TC * 4096) + (size_t)dt * 4096 + ec);

        if (t > 0) {
            const unsigned tgt = (unsigned)t;
            while (!__all(__hip_atomic_load(fp, __ATOMIC_RELAXED,
                                            __HIP_MEMORY_SCOPE_AGENT) >= tgt)) {}
        }

        // cooperative h-tile staging: 4096 u64 = 16 rows x 2048B, coalesced
        const unsigned long long* hsrc =
            (const unsigned long long*)((t & 1) ? hA : hB) + agbase;
#pragma unroll
        for (int j = 0; j < 8; j++) {
            int m = j * 512 + tid;
            unsigned long long v = __hip_atomic_load(hsrc + m, __ATOMIC_RELAXED,
                                                     __HIP_MEMORY_SCOPE_AGENT);
            *(unsigned long long*)(ldsA + (m >> 8) * 2064 + (m & 255) * 8) = v;
        }
        __syncthreads();

        // gates GEMM: 32 MFMA into one f32x4 (wave's 16 cols x 16 rows)
        f32x4 acc = (f32x4){0.f, 0.f, 0.f, 0.f};
        const char* apb = ldsA + (size_t)lr * 2064 + lq * 16;
        if (wv < 3) {
            const char* bp = ldsW + (size_t)(wv * 16 + lr) * 2064 + lq * 16;
#pragma unroll
            for (int kk = 0; kk < 32; kk++) {
                short8 a = *(const short8*)(apb + kk * 64);
                short8 bb = *(const short8*)(bp + kk * 64);
                acc = __builtin_amdgcn_mfma_f32_16x16x32_bf16(a, bb, acc, 0, 0, 0);
            }
        } else {
#pragma unroll
            for (int kk = 0; kk < 32; kk++) {
                short8 a = *(const short8*)(apb + kk * 64);
                acc = __builtin_amdgcn_mfma_f32_16x16x32_bf16(a, wreg[kk], acc, 0, 0, 0);
            }
        }

        // 4x4 transpose within 4-lane groups: lane ends with all 4 gates of one cell
        float a0 = acc[0], a1 = acc[1], a2 = acc[2], a3 = acc[3];
        {
            float x = __shfl_xor((l & 1) ? a0 : a1, 1);
            if (l & 1) a0 = x; else a1 = x;
            float y = __shfl_xor((l & 1) ? a2 : a3, 1);
            if (l & 1) a2 = y; else a3 = y;
            float z = __shfl_xor((l & 2) ? a0 : a2, 2);
            if (l & 2) a0 = z; else a2 = z;
            float w = __shfl_xor((l & 2) ? a1 : a3, 2);
            if (l & 2) a1 = w; else a3 = w;
        }
        const unsigned short* xs = (const unsigned short*)&xv;
        float pi = a0 + b2f(xs[0]) + bs.x;
        float pf = a1 + b2f(xs[1]) + bs.y;
        float pg = a2 + b2f(xs[2]) + bs.z;
        float po = a3 + b2f(xs[3]) + bs.w;
        float iv = sigm(pi), fv = sigm(pf), gv = tanhf(pg), ov = sigm(po);
        c2 = fv * c2 + iv * gv;
        float h = ov * tanhf(c2);

        // pack unit pairs via shfl (units 2u/2u+1 are lanes l / l^4) and store parity h
        unsigned hu = (unsigned)f2b(h);
        unsigned other = (unsigned)__shfl_xor((int)hu, 4);
        unsigned hp = hu | (other << 16);
        if (!(l & 4)) {
            unsigned* hout = (t & 1) ? hB : hA;
            __hip_atomic_store(hout + (size_t)b * 512 + (unit >> 1), hp,
                               __ATOMIC_RELAXED, __HIP_MEMORY_SCOPE_AGENT);
        }
        __syncthreads();   // drains all waves' h stores (vmcnt0) before signal
        if (tid == 0)
            __hip_atomic_store(fmine, (unsigned)(t + 1),
                               __ATOMIC_RELAXED, __HIP_MEMORY_SCOPE_AGENT);

        // off-critical-path stores AFTER signal
        if (LAYER == 0) {
            if (!(l & 4))
                ((unsigned*)y0)[((size_t)b * 256 + t) * 512 + (unit >> 1)] = hp;
        } else {
            out[((size_t)b * 256 + t) * 1024 + unit] = h;
            if (t == 255) {
                out[(size_t)128 * 256 * 1024 + (size_t)b * 1024 + unit] = h;
                out[(size_t)128 * 256 * 1024 + (size_t)128 * 1024 + (size_t)b * 1024 + unit] = c2;
            }
        }
    }
    // persist c for next chunk launch
    cbuf[(size_t)b * 1024 + unit] = c2;
}

// ---------------- host ----------------

extern "C" void kernel_launch(void* const* d_in, const int* in_sizes, int n_in,
                              void* d_out, int out_size, void* d_ws, size_t ws_size,
                              hipStream_t stream) {
    const float* x    = (const float*)d_in[0];
    const float* hx0  = (const float*)d_in[1];
    const float* cx0  = (const float*)d_in[2];
    const float* Wih0 = (const float*)d_in[3];
    const float* Whh0 = (const float*)d_in[4];
    const float* bih0 = (const float*)d_in[5];
    const float* bhh0 = (const float*)d_in[6];
    const float* Wih1 = (const float*)d_in[7];
    const float* Whh1 = (const float*)d_in[8];
    const float* bih1 = (const float*)d_in[9];
    const float* bhh1 = (const float*)d_in[10];
    float* out = (float*)d_out;

    const int B = 128, T = 256, I = 256, H = 1024, G4 = 4096;
    const unsigned SMEM_BYTES = 64 * 2064;  // 48 W rows + 16 A rows = 132096 B
    const int FLAGS_U32 = 8 * 32 * 16;      // per layer

    hipFuncSetAttribute((const void*)&k_lstm<0>, hipFuncAttributeMaxDynamicSharedMemorySize, SMEM_BYTES);
    hipFuncSetAttribute((const void*)&k_lstm<1>, hipFuncAttributeMaxDynamicSharedMemorySize, SMEM_BYTES);

    char* p = (char*)d_ws;
    auto alloc = [&](size_t bytes) { char* r = p; p += (bytes + 255) & ~(size_t)255; return r; };
    unsigned short* xbf   = (unsigned short*)alloc((size_t)B * T * I * 2);
    unsigned short* Wih0p = (unsigned short*)alloc((size_t)G4 * I * 2);
    unsigned short* Whh0p = (unsigned short*)alloc((size_t)G4 * H * 2);
    unsigned short* Wih1p = (unsigned short*)alloc((size_t)G4 * H * 2);
    unsigned short* Whh1p = (unsigned short*)alloc((size_t)G4 * H * 2);
    float* bias0 = (float*)alloc(G4 * 4);
    float* bias1 = (float*)alloc(G4 * 4);
    unsigned short* y0 = (unsigned short*)alloc((size_t)B * T * H * 2);
    unsigned* hA0 = (unsigned*)alloc((size_t)B * 512 * 4);
    unsigned* hB0 = (unsigned*)alloc((size_t)B * 512 * 4);
    unsigned* hA1 = (unsigned*)alloc((size_t)B * 512 * 4);
    unsigned* hB1 = (unsigned*)alloc((size_t)B * 512 * 4);
    float* c0 = (float*)alloc((size_t)B * H * 4);
    float* c1 = (float*)alloc((size_t)B * H * 4);
    unsigned* flags0 = (unsigned*)alloc((size_t)2 * FLAGS_U32 * 4);
    unsigned* flags1 = flags0 + FLAGS_U32;
    size_t fixed = (size_t)(p - (char*)d_ws);
    int TC = 256;
    while (TC > 1 && fixed + (size_t)B * TC * G4 * 2 + 256 > ws_size) TC >>= 1;
    unsigned short* xg = (unsigned short*)alloc((size_t)B * TC * G4 * 2);

    // converts + flag reset (flags carry absolute t+1, monotone within a launch)
    hipMemsetAsync(flags0, 0, (size_t)2 * FLAGS_U32 * 4, stream);
    k_f2b<<<(B * T * I / 4 + 255) / 256, 256, 0, stream>>>(x, xbf, B * T * I / 4);
    k_perm<<<(G4 * (I / 4) + 255) / 256, 256, 0, stream>>>(Wih0, Wih0p, I / 4);
    k_perm<<<(G4 * (H / 4) + 255) / 256, 256, 0, stream>>>(Whh0, Whh0p, H / 4);
    k_perm<<<(G4 * (H / 4) + 255) / 256, 256, 0, stream>>>(Wih1, Wih1p, H / 4);
    k_perm<<<(G4 * (H / 4) + 255) / 256, 256, 0, stream>>>(Whh1, Whh1p, H / 4);
    k_bias<<<16, 256, 0, stream>>>(bih0, bhh0, bih1, bhh1, bias0, bias1);
    k_init<<<256, 256, 0, stream>>>(hx0, cx0, hB0, hB1, c0, c1);

    // ---- layer 0 ----
    for (int t0 = 0; t0 < T; t0 += TC) {
        k_gemm<<<dim3(TC, 32), 256, 0, stream>>>(xbf, Wih0p, xg, I, t0, TC);
        int t0v = t0, TCv = TC;
        const unsigned short* Whp = Whh0p;
        const unsigned short* xgp = xg;
        const float* bp = bias0;
        float* cp = c0;
        unsigned* ha = hA0; unsigned* hb = hB0;
        unsigned short* y0p = y0;
        float* op = nullptr;
        unsigned* fl = flags0;
        void* args[] = {&Whp, &xgp, &bp, &cp, &ha, &hb, &y0p, &op, &fl, &t0v, &TCv};
        hipLaunchCooperativeKernel((const void*)&k_lstm<0>, dim3(256), dim3(512), args, SMEM_BYTES, stream);
    }
    // ---- layer 1 ----
    for (int t0 = 0; t0 < T; t0 += TC) {
        k_gemm<<<dim3(TC, 32), 256, 0, stream>>>(y0, Wih1p, xg, H, t0, TC);
        int t0v = t0, TCv = TC;
        const unsigned short* Whp = Whh1p;
        const unsigned short* xgp = xg;
        const float* bp = bias1;
        float* cp = c1;
        unsigned* ha = hA1; unsigned* hb = hB1;
        unsigned short* y0p = nullptr;
        float* op = out;
        unsigned* fl = flags1;
        void* args[] = {&Whp, &xgp, &bp, &cp, &ha, &hb, &y0p, &op, &fl, &t0v, &TCv};
        hipLaunchCooperativeKernel((const void*)&k_lstm<1>, dim3(256), dim3(512), args, SMEM_BYTES, stream);
    }
}